// Round 7
// baseline (316.197 us; speedup 1.0000x reference)
//
#include <hip/hip_runtime.h>
#include <hip/hip_bf16.h>
#include <math.h>

#define QN 128
#define SN 128
#define HN 32
#define CN (QN * SN)
#define TILE_R 64   // batch rows per block

// Block: 256 threads (4 waves), one q, 64 batch rows. Lane = row, wave w owns
// h-octet h0=w*8 -> W1/b1/W2 operands wave-uniform (SGPR broadcast).
// x staged coalesced into XOR-swizzled LDS (proven 0-conflict layout).
// KEY CHANGE vs round 6: x ds_reads are hoisted OUT of the FMA loop (16
// ds_read_b128 -> registers per row-half, one lgkmcnt drain), so the FMA loop
// contains ONLY s_load(W1) + v_fma -> lgkmcnt counts a single memory class
// and the scheduler can use counted waits instead of lgkmcnt(0) per iter.
__global__ __launch_bounds__(256, 4)
void divenc_kernel(const float* __restrict__ x,
                   const float* __restrict__ W1,
                   const float* __restrict__ b1,
                   const float* __restrict__ W2,
                   const float* __restrict__ b2,
                   float* __restrict__ out) {
  const int q    = blockIdx.x;
  const int b0   = blockIdx.y * TILE_R;
  const int tid  = threadIdx.x;
  const int lane = tid & 63;
  const int wid  = __builtin_amdgcn_readfirstlane(tid >> 6);
  const int h0   = wid * 8;  // uniform per wave

  __shared__ float xtile[TILE_R * SN];  // 32 KB, XOR-swizzled rows
  __shared__ float parts[4][TILE_R];

  const float* __restrict__ w1q = W1 + (size_t)q * (SN * HN);

  float b1v[8], w2v[8];
  #pragma unroll
  for (int j = 0; j < 8; ++j) {
    b1v[j] = b1[q * HN + h0 + j];   // uniform -> s_load
    w2v[j] = W2[q * HN + h0 + j];
  }
  const float b2q = b2[q];

  // ---- stage: coalesced (each instr = 2 contiguous 512B rows), short-lived regs
  const float* tb = x + (size_t)b0 * CN + (size_t)q * SN;
  #pragma unroll
  for (int i = 0; i < 8; ++i) {
    const int f = i * 256 + tid;
    const int r = f >> 5, c = f & 31;
    const float4 vv = *reinterpret_cast<const float4*>(tb + (size_t)r * CN + c * 4);
    *reinterpret_cast<float4*>(&xtile[r * SN + ((c ^ (r & 31)) << 2)]) = vv;
  }
  __syncthreads();

  float acc[8];
  #pragma unroll
  for (int j = 0; j < 8; ++j) acc[j] = 0.f;

  const int xsw = lane & 31;
  const float* xrow = &xtile[lane << 7];

  #pragma unroll
  for (int half = 0; half < 2; ++half) {
    // Phase A: lane's row half -> 16 float4 registers (only ds_reads here)
    float4 xv[16];
    #pragma unroll
    for (int i = 0; i < 16; ++i)
      xv[i] = *reinterpret_cast<const float4*>(
          xrow + (((half * 16 + i) ^ xsw) << 2));

    // Phase B: pure s_load(W1) + FMA loop (single lgkm memory class)
    #pragma unroll
    for (int i = 0; i < 16; ++i) {
      const int sq = half * 16 + i;
      const float* __restrict__ wrow = w1q + (sq << 2) * HN + h0;  // uniform
      #pragma unroll
      for (int u = 0; u < 4; ++u) {
        const float xu = (&xv[i].x)[u];
        #pragma unroll
        for (int j = 0; j < 8; ++j)
          acc[j] = fmaf(xu, wrow[u * HN + j], acc[j]);
      }
    }
  }

  // ---- epilogue: +b1, ELU, dot W2 over this wave's 8 h
  float part = 0.f;
  #pragma unroll
  for (int j = 0; j < 8; ++j) {
    float v = acc[j] + b1v[j];
    v = v > 0.f ? v : expm1f(v);
    part = fmaf(v, w2v[j], part);
  }
  parts[wid][lane] = part;
  __syncthreads();

  if (wid == 0) {
    const float o = parts[0][lane] + parts[1][lane] + parts[2][lane] +
                    parts[3][lane] + b2q;
    out[(size_t)(b0 + lane) * QN + q] = o;
  }
}

extern "C" void kernel_launch(void* const* d_in, const int* in_sizes, int n_in,
                              void* d_out, int out_size, void* d_ws, size_t ws_size,
                              hipStream_t stream) {
  const float* x  = (const float*)d_in[0];
  const float* W1 = (const float*)d_in[1];
  const float* b1 = (const float*)d_in[2];
  const float* W2 = (const float*)d_in[3];
  const float* b2 = (const float*)d_in[4];
  float* out = (float*)d_out;

  const int B = in_sizes[0] / CN;  // 2048
  dim3 grid(QN, B / TILE_R);
  divenc_kernel<<<grid, 256, 0, stream>>>(x, W1, b1, W2, b2, out);
}

// Round 8
// 28.865 us; speedup vs baseline: 10.9541x; 10.9541x over previous
//
#include <hip/hip_runtime.h>
#include <hip/hip_bf16.h>
#include <math.h>

#define QN 128
#define SN 128
#define HN 32
#define CN (QN * SN)
#define TILE_R 128   // batch rows per block

using half8  = __attribute__((ext_vector_type(8))) _Float16;
using half4v = __attribute__((ext_vector_type(4))) _Float16;
using floatx4 = __attribute__((ext_vector_type(4))) float;

// Grouped-GEMM via MFMA. Block: 256 threads (4 waves), one q, 128 batch rows.
// Wave w owns rows w*32..w*32+31 (two 16-row M-tiles). N = HN = 32 -> two
// 16-col N-tiles. K = SN = 128 -> 4 MFMA (16x16x32 f16) per (M,N) tile.
// x: staged coalesced (R6-proven global pattern) with fp32->fp16 convert into
// XOR-swizzled LDS; A-frag = one ds_read_b128 per (mt,kk), conflict-free.
// W1: B-frags built once per wave from global (L1/L2-hot, q-shared across all
// 16 row-blocks on the same XCD since gridDim.x=128 -> bid%8 = q%8).
// Epilogue: +b1, ELU, *W2, 4-step shfl_xor reduce over the 16 h-lanes, +b2.
__global__ __launch_bounds__(256, 4)
void divenc_kernel(const float* __restrict__ x,
                   const float* __restrict__ W1,
                   const float* __restrict__ b1,
                   const float* __restrict__ W2,
                   const float* __restrict__ b2,
                   float* __restrict__ out) {
  const int q    = blockIdx.x;
  const int b0   = blockIdx.y * TILE_R;
  const int tid  = threadIdx.x;
  const int lane = tid & 63;
  const int wid  = __builtin_amdgcn_readfirstlane(tid >> 6);
  const int nA   = lane & 15;   // n-col within tile / m-row for A-frag
  const int koct = lane >> 4;   // k-octet 0..3

  __shared__ _Float16 xs[TILE_R * SN];  // 32 KB, [row][slot^ (row&15)] fp16

  // ---- B-frags: W1[q][k][n], lane holds k = kk*32 + koct*8 + i, n = n0*16+nA.
  // 64 scalar loads, coalesced across lanes (16 consecutive n), L1/L2-hot.
  const float* __restrict__ w1q = W1 + (size_t)q * (SN * HN);
  half8 bf[2][4];
  #pragma unroll
  for (int n0 = 0; n0 < 2; ++n0) {
    #pragma unroll
    for (int kk = 0; kk < 4; ++kk) {
      #pragma unroll
      for (int i = 0; i < 8; ++i) {
        const int k = kk * 32 + koct * 8 + i;
        bf[n0][kk][i] = (_Float16)w1q[k * HN + n0 * 16 + nA];
      }
    }
  }

  // ---- stage x: f = i*256+tid -> r = f>>5, c = f&31 (float4 col). Per-instr:
  // 32 lanes cover one full contiguous 512B row segment (proven 0-overfetch).
  // Convert 4 fp32 -> 4 fp16, write 8B to swizzled half-slot.
  const float* tb = x + (size_t)b0 * CN + (size_t)q * SN;
  #pragma unroll
  for (int i = 0; i < 16; ++i) {
    const int f = i * 256 + tid;
    const int r = f >> 5, c = f & 31;
    const float4 v = *reinterpret_cast<const float4*>(tb + (size_t)r * CN + c * 4);
    half4v h;
    h[0] = (_Float16)v.x; h[1] = (_Float16)v.y;
    h[2] = (_Float16)v.z; h[3] = (_Float16)v.w;
    *reinterpret_cast<half4v*>(
        &xs[r * SN + (((c >> 1) ^ (r & 15)) << 3) + (c & 1) * 4]) = h;
  }
  __syncthreads();

  // ---- MFMA: A-frag lane holds X[row = r0+nA][k = kk*32 + koct*8 + i]
  floatx4 z = {0.f, 0.f, 0.f, 0.f};
  floatx4 acc[2][2];
  acc[0][0] = z; acc[0][1] = z; acc[1][0] = z; acc[1][1] = z;

  #pragma unroll
  for (int mt = 0; mt < 2; ++mt) {
    const int row = wid * 32 + mt * 16 + nA;
    #pragma unroll
    for (int kk = 0; kk < 4; ++kk) {
      const int slot = kk * 4 + koct;
      const half8 af = *reinterpret_cast<const half8*>(
          &xs[row * SN + ((slot ^ (row & 15)) << 3)]);
      acc[mt][0] = __builtin_amdgcn_mfma_f32_16x16x32_f16(af, bf[0][kk], acc[mt][0], 0, 0, 0);
      acc[mt][1] = __builtin_amdgcn_mfma_f32_16x16x32_f16(af, bf[1][kk], acc[mt][1], 0, 0, 0);
    }
  }

  // ---- epilogue. C/D: col = nA (h within n-tile), row = r0 + koct*4 + reg.
  const float b1a = b1[q * HN + nA],      b1b = b1[q * HN + 16 + nA];
  const float w2a = W2[q * HN + nA],      w2b = W2[q * HN + 16 + nA];
  const float b2q = b2[q];

  #pragma unroll
  for (int mt = 0; mt < 2; ++mt) {
    #pragma unroll
    for (int reg = 0; reg < 4; ++reg) {
      float v0 = acc[mt][0][reg] + b1a;
      v0 = v0 > 0.f ? v0 : expm1f(v0);
      float v1 = acc[mt][1][reg] + b1b;
      v1 = v1 > 0.f ? v1 : expm1f(v1);
      float t = fmaf(v0, w2a, v1 * w2b);
      t += __shfl_xor(t, 1);
      t += __shfl_xor(t, 2);
      t += __shfl_xor(t, 4);
      t += __shfl_xor(t, 8);
      if (nA == 0) {
        const int row = wid * 32 + mt * 16 + koct * 4 + reg;
        out[(size_t)(b0 + row) * QN + q] = t + b2q;
      }
    }
  }
}

extern "C" void kernel_launch(void* const* d_in, const int* in_sizes, int n_in,
                              void* d_out, int out_size, void* d_ws, size_t ws_size,
                              hipStream_t stream) {
  const float* x  = (const float*)d_in[0];
  const float* W1 = (const float*)d_in[1];
  const float* b1 = (const float*)d_in[2];
  const float* W2 = (const float*)d_in[3];
  const float* b2 = (const float*)d_in[4];
  float* out = (float*)d_out;

  const int B = in_sizes[0] / CN;  // 2048
  dim3 grid(QN, B / TILE_R);
  divenc_kernel<<<grid, 256, 0, stream>>>(x, W1, b1, W2, b2, out);
}